// Round 5
// baseline (188.770 us; speedup 1.0000x reference)
//
#include <hip/hip_runtime.h>
#include <hip/hip_bf16.h>

typedef unsigned int u32;
typedef unsigned short u16;
typedef unsigned char u8;

#define N_BATCH 8192
#define EMB_DIM 128
#define MARGIN 1.0f
#define CAP 192          // max members/class (mean 128, sd 11.2 -> 5.7 sigma)
#define BIGF 3.3e38f
#define GRAM_JOBS 2080   // 64*65/2 triangular 128x128 tiles
#define FUSED_GRID 768

typedef __attribute__((ext_vector_type(8))) short bf16x8;   // 8 bf16 = 4 VGPRs
typedef __attribute__((ext_vector_type(4))) float f32x4;    // MFMA 16x16 acc

// async global->LDS, 16B/lane; lds dest is wave-uniform base (+lane*16 implicit)
__device__ inline void async_ld16(const void* g, void* l) {
    __builtin_amdgcn_global_load_lds(
        (const __attribute__((address_space(1))) unsigned int*)g,
        (__attribute__((address_space(3))) unsigned int*)l, 16, 0, 0);
}

// ---------------------------------------------------------------------------
// ctrl layout (u32 words, zeroed by memset node):
//  [0] gram job ticket   [1] gram done count   [2] class finalize ticket
//  [4],[5] totals (float sum, float count)     [8..71] classCnt[64]
// ---------------------------------------------------------------------------

// Kernel 1: bf16 cast + row sq-norms + negmin init + label pack + class lists.
__global__ __launch_bounds__(256) void k_prep(const float* __restrict__ emb,
                                              const int* __restrict__ labels,
                                              u16* __restrict__ ebf,
                                              float* __restrict__ sq,
                                              u32* __restrict__ negmin,
                                              u8* __restrict__ labels8,
                                              u32* __restrict__ ctrl,
                                              u32* __restrict__ classList) {
    int t = threadIdx.x;
    int gt = blockIdx.x * 256 + t;
    int r = blockIdx.x * 8 + (t >> 5);
    int l32 = t & 31;
    float4 x = ((const float4*)emb)[(size_t)r * 32 + l32];
    u32 ux = __float_as_uint(x.x), uy = __float_as_uint(x.y);
    u32 uz = __float_as_uint(x.z), uw = __float_as_uint(x.w);
    ushort4 b;
    b.x = (u16)((ux + 0x7fffu + ((ux >> 16) & 1u)) >> 16);   // RNE fp32->bf16
    b.y = (u16)((uy + 0x7fffu + ((uy >> 16) & 1u)) >> 16);
    b.z = (u16)((uz + 0x7fffu + ((uz >> 16) & 1u)) >> 16);
    b.w = (u16)((uw + 0x7fffu + ((uw >> 16) & 1u)) >> 16);
    ((ushort4*)ebf)[(size_t)r * 32 + l32] = b;

    float v = fmaf(x.x, x.x, fmaf(x.y, x.y, fmaf(x.z, x.z, x.w * x.w)));
    v += __shfl_down(v, 16, 64);   // 32-lane row reduce
    v += __shfl_down(v, 8, 64);
    v += __shfl_down(v, 4, 64);
    v += __shfl_down(v, 2, 64);
    v += __shfl_down(v, 1, 64);
    if (l32 == 0) sq[r] = v;

    if (gt < N_BATCH) {
        negmin[gt] = 0x7f7fffffu;   // FLT_MAX bits; dists clamped >=0 so uint order == float order
        int lbl = labels[gt];
        labels8[gt] = (u8)lbl;
        u32 slot = atomicAdd(&ctrl[8 + lbl], 1u);
        if (slot < CAP) classList[lbl * CAP + slot] = (u32)gt;
    }
}

// ---------------------------------------------------------------------------
// Kernel 2: ticket-driven triangular Gram -> negmin atomicMin; then blocks
// 0..63 spin for gram completion and do per-class pair losses; ticket-last
// class block writes the final scalar. No co-residency assumption.
// ---------------------------------------------------------------------------
__global__ __launch_bounds__(256, 3) void k_fused(
    const u16* __restrict__ ebf, const float* __restrict__ sq,
    const u8* __restrict__ labels8, u32* __restrict__ negmin,
    u32* __restrict__ ctrl, const u32* __restrict__ classList,
    float* __restrict__ out) {
    __shared__ uint4 smem4[3072];   // 48 KB: gram B-tile uses 32 KB; class E-tile 48 KB
    __shared__ u32 lmem[CAP];
    __shared__ float lnm[CAP], lsq[CAP];
    __shared__ float redS[4], redC[4];
    __shared__ u32 sjob;

    const int t = threadIdx.x;
    const int blk = blockIdx.x;
    const int lane = t & 63, w = t >> 6;
    const int c16 = lane & 15, quad = lane >> 4;
    float* totalsF = (float*)(ctrl + 4);

    // ================= Gram phase (work-stealing ticket) =================
    for (;;) {
        __syncthreads();                     // protect LDS + sjob reuse
        if (t == 0) sjob = atomicAdd(&ctrl[0], 1u);
        __syncthreads();
        u32 job = sjob;
        if (job >= GRAM_JOBS) break;

        // triangular decode: job -> (bx, by), by >= bx
        int idx = (int)job;
        float ff = (129.0f - sqrtf(16641.0f - 8.0f * (float)idx)) * 0.5f;
        int bx = (int)ff;
        if (bx > 63) bx = 63;
        while (bx > 0 && idx < bx * 64 - (bx * (bx - 1)) / 2) --bx;
        while (idx >= (bx + 1) * 64 - ((bx + 1) * bx) / 2) ++bx;
        int by = bx + idx - (bx * 64 - (bx * (bx - 1)) / 2);
        const int R = bx * 128, C = by * 128;
        const bool diag = (bx == by);

        uint4* Bs = smem4;
        const uint4* gE = (const uint4*)ebf;
#pragma unroll
        for (int it = 0; it < 8; ++it) {     // stage B tile via DMA, XOR swizzle at source
            int s = w * 512 + it * 64 + lane;
            int row = s >> 4, chPos = s & 15;
            int ch = chPos ^ (row & 15);
            async_ld16(gE + (size_t)(C + row) * 16 + ch, Bs + (w * 512 + it * 64));
        }

        const int mb = (w & 1) * 64;
        const int nb = (w >> 1) * 64;
        const bf16x8* gA8 = (const bf16x8*)ebf;
        bf16x8 a[4];
#pragma unroll
        for (int i = 0; i < 4; ++i)
            a[i] = gA8[(size_t)(R + mb + i * 16 + c16) * 16 + quad];

        // hoisted epilogue metadata: overlap L2 latency with staging + MFMA
        float cs_[4]; int cl_[4];
#pragma unroll
        for (int j = 0; j < 4; ++j) {
            int gc = C + nb + j * 16 + c16;
            cs_[j] = sq[gc]; cl_[j] = labels8[gc];
        }
        float rs_[16]; int rl_[16];
#pragma unroll
        for (int i = 0; i < 4; ++i)
#pragma unroll
            for (int rg = 0; rg < 4; ++rg) {
                int gr = R + mb + i * 16 + quad * 4 + rg;
                rs_[i * 4 + rg] = sq[gr]; rl_[i * 4 + rg] = labels8[gr];
            }

        f32x4 acc[4][4];
#pragma unroll
        for (int i = 0; i < 4; ++i)
#pragma unroll
            for (int j = 0; j < 4; ++j) acc[i][j] = (f32x4){0.f, 0.f, 0.f, 0.f};

        __syncthreads();   // drains LDS-DMA

        const bf16x8* Bs8 = (const bf16x8*)Bs;
#pragma unroll
        for (int kc = 0; kc < 4; ++kc) {
            int kch = kc * 4 + quad;
            bf16x8 bfr[4];
#pragma unroll
            for (int j = 0; j < 4; ++j) {
                int br = nb + j * 16 + c16;
                bfr[j] = Bs8[br * 16 + (kch ^ (br & 15))];
            }
            bf16x8 an[4];
            if (kc < 3) {
                int kn = (kc + 1) * 4 + quad;
#pragma unroll
                for (int i = 0; i < 4; ++i)
                    an[i] = gA8[(size_t)(R + mb + i * 16 + c16) * 16 + kn];
            }
#pragma unroll
            for (int i = 0; i < 4; ++i)
#pragma unroll
                for (int j = 0; j < 4; ++j)
                    acc[i][j] = __builtin_amdgcn_mfma_f32_16x16x32_bf16(a[i], bfr[j], acc[i][j], 0, 0, 0);
            if (kc < 3) {
#pragma unroll
                for (int i = 0; i < 4; ++i) a[i] = an[i];
            }
        }
        __syncthreads();   // B reads done; reuse LDS

        u32* rowmin = (u32*)smem4;
        u32* colmin = rowmin + 128;
        rowmin[t] = 0x7f7fffffu;   // t<256 inits both halves
        __syncthreads();

        float cm[4] = {BIGF, BIGF, BIGF, BIGF};
#pragma unroll
        for (int i = 0; i < 4; ++i) {
            const int rowbase = mb + i * 16 + quad * 4;
            float rm[4] = {BIGF, BIGF, BIGF, BIGF};
#pragma unroll
            for (int j = 0; j < 4; ++j)
#pragma unroll
                for (int rg = 0; rg < 4; ++rg) {
                    // C/D layout (m89/m91): D[row=quad*4+rg][col=lane&15]
                    float d = fmaf(-2.f, acc[i][j][rg], rs_[i * 4 + rg] + cs_[j]);
                    bool same = (rl_[i * 4 + rg] == cl_[j]);
                    float cand = same ? BIGF : fmaxf(d, 0.f);
                    rm[rg] = fminf(rm[rg], cand);
                    cm[j] = fminf(cm[j], cand);
                }
#pragma unroll
            for (int rg = 0; rg < 4; ++rg) {
                float v = rm[rg];
                v = fminf(v, __shfl_xor(v, 1, 64));
                v = fminf(v, __shfl_xor(v, 2, 64));
                v = fminf(v, __shfl_xor(v, 4, 64));
                v = fminf(v, __shfl_xor(v, 8, 64));
                if (c16 == 0) atomicMin(&rowmin[rowbase + rg], __float_as_uint(v));
            }
        }
        if (!diag) {
#pragma unroll
            for (int j = 0; j < 4; ++j) {
                float v = cm[j];
                v = fminf(v, __shfl_xor(v, 16, 64));
                v = fminf(v, __shfl_xor(v, 32, 64));
                if (quad == 0) atomicMin(&colmin[nb + j * 16 + c16], __float_as_uint(v));
            }
        }
        __syncthreads();
        if (t < 128) atomicMin(&negmin[R + t], rowmin[t]);
        else if (!diag) atomicMin(&negmin[C + t - 128], colmin[t - 128]);
        __syncthreads();                     // all lanes' atomics drained (vmcnt(0) at barrier)
        if (t == 0) { __threadfence(); atomicAdd(&ctrl[1], 1u); }
    }

    // ================= Class phase (blocks 0..63) =================
    if (blk >= 64) return;
    const int c = blk;
    if (t == 0) {
        while (atomicAdd(&ctrl[1], 0u) < GRAM_JOBS) __builtin_amdgcn_s_sleep(1);
    }
    __syncthreads();
    __threadfence();   // acquire

    int n = (int)atomicAdd(&ctrl[8 + c], 0u); if (n > CAP) n = CAP;
    if (t < CAP) {
        u32 m = (t < n) ? classList[c * CAP + t] : 0u;
        lmem[t] = m;
        // negmin was atomic-written this kernel -> read with device-scope atomic
        lnm[t] = (t < n) ? __uint_as_float(atomicOr(&negmin[m], 0u)) : 0.f;
        lsq[t] = (t < n) ? sq[m] : 0.f;
    }
    __syncthreads();
    uint4* Es = smem4;
    const uint4* gE = (const uint4*)ebf;
#pragma unroll
    for (int it = 0; it < 12; ++it) {        // gather 192 rows, XOR-swizzled
        int s = t + it * 256;
        int row = s >> 4, ch = s & 15;
        u32 m = lmem[row];                   // pad rows -> row 0 (masked below)
        Es[row * 16 + (ch ^ (row & 15))] = gE[(size_t)m * 16 + ch];
    }
    __syncthreads();

    const bf16x8* Es8 = (const bf16x8*)Es;
    float ssum = 0.f, scnt = 0.f;
    for (int cp = 0; cp < 3; ++cp) {         // col panels of 64; wave w owns rows w*48..+47
        if (cp * 64 >= n) break;             // block-uniform
        f32x4 acc[3][4];
#pragma unroll
        for (int i = 0; i < 3; ++i)
#pragma unroll
            for (int j = 0; j < 4; ++j) acc[i][j] = (f32x4){0.f, 0.f, 0.f, 0.f};
#pragma unroll
        for (int kc = 0; kc < 4; ++kc) {
            int kch = kc * 4 + quad;
            bf16x8 a3[3], b4[4];
#pragma unroll
            for (int i = 0; i < 3; ++i) {
                int ar = w * 48 + i * 16 + c16;
                a3[i] = Es8[ar * 16 + (kch ^ (ar & 15))];
            }
#pragma unroll
            for (int j = 0; j < 4; ++j) {
                int br = cp * 64 + j * 16 + c16;
                b4[j] = Es8[br * 16 + (kch ^ (br & 15))];
            }
#pragma unroll
            for (int i = 0; i < 3; ++i)
#pragma unroll
                for (int j = 0; j < 4; ++j)
                    acc[i][j] = __builtin_amdgcn_mfma_f32_16x16x32_bf16(a3[i], b4[j], acc[i][j], 0, 0, 0);
        }
        float lsqq[4]; u32 oq[4]; bool qv[4];
#pragma unroll
        for (int j = 0; j < 4; ++j) {
            int q = cp * 64 + j * 16 + c16;
            qv[j] = (q < n);
            lsqq[j] = qv[j] ? lsq[q] : 0.f;
            oq[j] = qv[j] ? lmem[q] : 0u;            // 0 sentinel: opp<0 never true
        }
#pragma unroll
        for (int i = 0; i < 3; ++i) {
            int pb = w * 48 + i * 16 + quad * 4;
            float rcst[4]; u32 opp[4];
#pragma unroll
            for (int rg = 0; rg < 4; ++rg) {
                int p = pb + rg;
                bool pv = (p < n);
                rcst[rg] = pv ? (lsq[p] - lnm[p] + MARGIN) : -BIGF;
                opp[rg] = pv ? lmem[p] : 0xffffffffu;   // max sentinel: opp<oq never true
            }
#pragma unroll
            for (int j = 0; j < 4; ++j)
#pragma unroll
                for (int rg = 0; rg < 4; ++rg) {
                    float val = fmaf(-2.f, acc[i][j][rg], rcst[rg] + lsqq[j]);
                    bool ok = qv[j] && (opp[rg] < oq[j]) && (val > 0.f);
                    if (ok) { ssum += val; scnt += 1.f; }
                }
        }
    }
#pragma unroll
    for (int off2 = 32; off2 > 0; off2 >>= 1) {
        ssum += __shfl_down(ssum, off2, 64);
        scnt += __shfl_down(scnt, off2, 64);
    }
    if (lane == 0) { redS[w] = ssum; redC[w] = scnt; }
    __syncthreads();
    if (t == 0) {
        atomicAdd(&totalsF[0], redS[0] + redS[1] + redS[2] + redS[3]);
        atomicAdd(&totalsF[1], redC[0] + redC[1] + redC[2] + redC[3]);
        __threadfence();
        u32 tk = atomicAdd(&ctrl[2], 1u);
        if (tk == 63u) {                     // last class block: finalize
            __threadfence();
            float fs = atomicAdd(&totalsF[0], 0.f);
            float fc = atomicAdd(&totalsF[1], 0.f);
            out[0] = fs / fmaxf(fc, 1.0f);
        }
    }
}

// ---------------------------------------------------------------------------
extern "C" void kernel_launch(void* const* d_in, const int* in_sizes, int n_in,
                              void* d_out, int out_size, void* d_ws, size_t ws_size,
                              hipStream_t stream) {
    const float* emb = (const float*)d_in[0];
    const int* labels = (const int*)d_in[1];

    char* wsp = (char*)d_ws;
    u16* ebf = (u16*)wsp;
    size_t off = (size_t)N_BATCH * EMB_DIM * sizeof(u16);                // 2 MB
    float* sq = (float*)(wsp + off);       off += (size_t)N_BATCH * 4;   // 32 KB
    u32* negmin = (u32*)(wsp + off);       off += (size_t)N_BATCH * 4;   // 32 KB
    u8* labels8 = (u8*)(wsp + off);        off += N_BATCH;               // 8 KB
    u32* ctrl = (u32*)(wsp + off);         off += 512;
    u32* classList = (u32*)(wsp + off);    off += (size_t)64 * CAP * 4;  // 48 KB

    hipMemsetAsync(ctrl, 0, 512, stream);
    k_prep<<<N_BATCH / 8, 256, 0, stream>>>(emb, labels, ebf, sq, negmin,
                                            labels8, ctrl, classList);
    k_fused<<<FUSED_GRID, 256, 0, stream>>>(ebf, sq, labels8, negmin, ctrl,
                                            classList, (float*)d_out);
}

// Round 6
// 155.223 us; speedup vs baseline: 1.2161x; 1.2161x over previous
//
#include <hip/hip_runtime.h>
#include <hip/hip_bf16.h>

typedef unsigned int u32;
typedef unsigned short u16;
typedef unsigned char u8;
typedef unsigned long long u64;

#define N_BATCH 8192
#define EMB_DIM 128
#define MARGIN 1.0f
#define CAP 192          // max members/class (mean 128, sd 11.2 -> 5.7 sigma)
#define BIGF 3.3e38f
#define GRAM_JOBS 2080   // 64*65/2 triangular 128x128 tiles

// ctrl u32 indices (separate 128B cachelines for hot words)
#define C_DONE 32        // gram done counter
#define C_TOT  64        // [64],[65] float totals
#define C_TK   96        // class finalize ticket

typedef __attribute__((ext_vector_type(8))) short bf16x8;   // 8 bf16 = 4 VGPRs
typedef __attribute__((ext_vector_type(4))) float f32x4;    // MFMA 16x16 acc

// async global->LDS, 16B/lane; lds dest is wave-uniform base (+lane*16 implicit)
__device__ inline void async_ld16(const void* g, void* l) {
    __builtin_amdgcn_global_load_lds(
        (const __attribute__((address_space(1))) unsigned int*)g,
        (__attribute__((address_space(3))) unsigned int*)l, 16, 0, 0);
}

// ---------------------------------------------------------------------------
// Kernel 1: bf16 cast + row sq-norms + negmin init + u8 label pack + ctrl zero.
// ---------------------------------------------------------------------------
__global__ __launch_bounds__(256) void k_prep(const float* __restrict__ emb,
                                              const int* __restrict__ labels,
                                              u16* __restrict__ ebf,
                                              float* __restrict__ sq,
                                              u32* __restrict__ negmin,
                                              u8* __restrict__ labels8,
                                              u32* __restrict__ ctrl) {
    int t = threadIdx.x;
    int gt = blockIdx.x * 256 + t;
    int r = blockIdx.x * 8 + (t >> 5);
    int l32 = t & 31;
    float4 x = ((const float4*)emb)[(size_t)r * 32 + l32];
    u32 ux = __float_as_uint(x.x), uy = __float_as_uint(x.y);
    u32 uz = __float_as_uint(x.z), uw = __float_as_uint(x.w);
    ushort4 b;
    b.x = (u16)((ux + 0x7fffu + ((ux >> 16) & 1u)) >> 16);   // RNE fp32->bf16
    b.y = (u16)((uy + 0x7fffu + ((uy >> 16) & 1u)) >> 16);
    b.z = (u16)((uz + 0x7fffu + ((uz >> 16) & 1u)) >> 16);
    b.w = (u16)((uw + 0x7fffu + ((uw >> 16) & 1u)) >> 16);
    ((ushort4*)ebf)[(size_t)r * 32 + l32] = b;

    float v = fmaf(x.x, x.x, fmaf(x.y, x.y, fmaf(x.z, x.z, x.w * x.w)));
    v += __shfl_down(v, 16, 64);   // 32-lane row reduce
    v += __shfl_down(v, 8, 64);
    v += __shfl_down(v, 4, 64);
    v += __shfl_down(v, 2, 64);
    v += __shfl_down(v, 1, 64);
    if (l32 == 0) sq[r] = v;

    if (gt < N_BATCH) {
        negmin[gt] = 0x7f7fffffu;   // FLT_MAX bits; dists clamped >=0 -> uint order == float order
        labels8[gt] = (u8)labels[gt];
    }
    if (blockIdx.x == 0 && t < 128) ctrl[t] = 0u;   // done, totals, ticket all < 128
}

// ---------------------------------------------------------------------------
// Kernel 2 (grid 2080): block b does gram job b (triangular 128x128 tile ->
// negmin atomicMin, fence-free), increments done counter; blocks 0..63 then
// build their class member list (ballot scan of labels8), spin on the done
// counter (relaxed atomic load + s_sleep), and compute per-class pair losses
// with MFMA frags read directly from L2-hot ebf. Ticket-last block finalizes.
// ---------------------------------------------------------------------------
__global__ __launch_bounds__(256, 4) void k_fused(
    const u16* __restrict__ ebf, const float* __restrict__ sq,
    const u8* __restrict__ labels8, u32* __restrict__ negmin,
    u32* __restrict__ ctrl, float* __restrict__ out) {
    __shared__ uint4 smem4[2048];   // 32 KB gram B-tile (reused as rowmin/colmin)
    __shared__ u32 lmem[CAP];
    __shared__ float lnm[CAP], lsq[CAP];
    __shared__ float redS[4], redC[4];
    __shared__ u32 sN;

    const int t = threadIdx.x;
    const int blk = blockIdx.x;
    const int lane = t & 63, w = t >> 6;
    const int c16 = lane & 15, quad = lane >> 4;
    const bf16x8* gA8 = (const bf16x8*)ebf;

    // ================= Gram job (static: job = blk) =================
    {
        int idx = blk;   // triangular decode: idx -> (bx, by), by >= bx
        float ff = (129.0f - sqrtf(16641.0f - 8.0f * (float)idx)) * 0.5f;
        int bx = (int)ff;
        if (bx > 63) bx = 63;
        while (bx > 0 && idx < bx * 64 - (bx * (bx - 1)) / 2) --bx;
        while (idx >= (bx + 1) * 64 - ((bx + 1) * bx) / 2) ++bx;
        int by = bx + idx - (bx * 64 - (bx * (bx - 1)) / 2);
        const int R = bx * 128, C = by * 128;
        const bool diag = (bx == by);

        uint4* Bs = smem4;
        const uint4* gE = (const uint4*)ebf;
#pragma unroll
        for (int it = 0; it < 8; ++it) {     // stage B tile via DMA, XOR swizzle at source
            int s = w * 512 + it * 64 + lane;
            int row = s >> 4, chPos = s & 15;
            int ch = chPos ^ (row & 15);
            async_ld16(gE + (size_t)(C + row) * 16 + ch, Bs + (w * 512 + it * 64));
        }

        const int mb = (w & 1) * 64;
        const int nb = (w >> 1) * 64;
        bf16x8 a[4];
#pragma unroll
        for (int i = 0; i < 4; ++i)
            a[i] = gA8[(size_t)(R + mb + i * 16 + c16) * 16 + quad];

        // hoisted epilogue metadata (overlaps DMA + MFMA latency)
        float cs_[4]; int cl_[4];
#pragma unroll
        for (int j = 0; j < 4; ++j) {
            int gc = C + nb + j * 16 + c16;
            cs_[j] = sq[gc]; cl_[j] = labels8[gc];
        }
        float rs_[16]; int rl_[16];
#pragma unroll
        for (int i = 0; i < 4; ++i)
#pragma unroll
            for (int rg = 0; rg < 4; ++rg) {
                int gr = R + mb + i * 16 + quad * 4 + rg;
                rs_[i * 4 + rg] = sq[gr]; rl_[i * 4 + rg] = labels8[gr];
            }

        f32x4 acc[4][4];
#pragma unroll
        for (int i = 0; i < 4; ++i)
#pragma unroll
            for (int j = 0; j < 4; ++j) acc[i][j] = (f32x4){0.f, 0.f, 0.f, 0.f};

        __syncthreads();   // drains LDS-DMA

        const bf16x8* Bs8 = (const bf16x8*)Bs;
#pragma unroll
        for (int kc = 0; kc < 4; ++kc) {
            int kch = kc * 4 + quad;
            bf16x8 bfr[4];
#pragma unroll
            for (int j = 0; j < 4; ++j) {
                int br = nb + j * 16 + c16;
                bfr[j] = Bs8[br * 16 + (kch ^ (br & 15))];
            }
            bf16x8 an[4];
            if (kc < 3) {
                int kn = (kc + 1) * 4 + quad;
#pragma unroll
                for (int i = 0; i < 4; ++i)
                    an[i] = gA8[(size_t)(R + mb + i * 16 + c16) * 16 + kn];
            }
#pragma unroll
            for (int i = 0; i < 4; ++i)
#pragma unroll
                for (int j = 0; j < 4; ++j)
                    acc[i][j] = __builtin_amdgcn_mfma_f32_16x16x32_bf16(a[i], bfr[j], acc[i][j], 0, 0, 0);
            if (kc < 3) {
#pragma unroll
                for (int i = 0; i < 4; ++i) a[i] = an[i];
            }
        }
        __syncthreads();   // B reads done; reuse LDS

        u32* rowmin = (u32*)smem4;
        u32* colmin = rowmin + 128;
        rowmin[t] = 0x7f7fffffu;   // t<256 inits both halves
        __syncthreads();

        float cm[4] = {BIGF, BIGF, BIGF, BIGF};
#pragma unroll
        for (int i = 0; i < 4; ++i) {
            const int rowbase = mb + i * 16 + quad * 4;
            float rm[4] = {BIGF, BIGF, BIGF, BIGF};
#pragma unroll
            for (int j = 0; j < 4; ++j)
#pragma unroll
                for (int rg = 0; rg < 4; ++rg) {
                    // C/D layout (m89/m91): D[row=quad*4+rg][col=lane&15]
                    float d = fmaf(-2.f, acc[i][j][rg], rs_[i * 4 + rg] + cs_[j]);
                    bool same = (rl_[i * 4 + rg] == cl_[j]);
                    float cand = same ? BIGF : fmaxf(d, 0.f);
                    rm[rg] = fminf(rm[rg], cand);
                    cm[j] = fminf(cm[j], cand);
                }
#pragma unroll
            for (int rg = 0; rg < 4; ++rg) {
                float v = rm[rg];
                v = fminf(v, __shfl_xor(v, 1, 64));
                v = fminf(v, __shfl_xor(v, 2, 64));
                v = fminf(v, __shfl_xor(v, 4, 64));
                v = fminf(v, __shfl_xor(v, 8, 64));
                if (c16 == 0) atomicMin(&rowmin[rowbase + rg], __float_as_uint(v));
            }
        }
        if (!diag) {
#pragma unroll
            for (int j = 0; j < 4; ++j) {
                float v = cm[j];
                v = fminf(v, __shfl_xor(v, 16, 64));
                v = fminf(v, __shfl_xor(v, 32, 64));
                if (quad == 0) atomicMin(&colmin[nb + j * 16 + c16], __float_as_uint(v));
            }
        }
        __syncthreads();
        if (t < 128) atomicMin(&negmin[R + t], rowmin[t]);
        else if (!diag) atomicMin(&negmin[C + t - 128], colmin[t - 128]);
        __syncthreads();   // every wave drains vmcnt(0): all negmin atomics committed
        if (t == 0) atomicAdd(&ctrl[C_DONE], 1u);   // relaxed release (barrier = vmcnt0)
    }

    // ================= Class phase (blocks 0..63) =================
    if (blk >= 64) return;
    const int c = blk;
    float* totalsF = (float*)(ctrl + C_TOT);

    // build member list by ballot scan of labels8 (overlaps remaining gram work)
    if (t == 0) sN = 0u;
    __syncthreads();
    for (int ch = 0; ch < 32; ++ch) {
        int row = ch * 256 + t;
        bool m = (labels8[row] == (u8)c);
        u64 mask = __ballot(m);
        u32 base = 0;
        if (lane == 0 && mask) base = atomicAdd(&sN, (u32)__popcll(mask));
        base = __shfl(base, 0, 64);
        if (m) {
            u32 p = base + (u32)__popcll(mask & ((1ull << lane) - 1ull));
            if (p < CAP) lmem[p] = (u32)row;
        }
    }
    __syncthreads();
    int n = (int)sN; if (n > CAP) n = CAP;
    if (t < CAP && t >= n) lmem[t] = 0u;   // pad -> row 0 (masked below)

    // spin until all gram jobs committed (relaxed atomic load, gentle)
    if (t == 0) {
        while (__hip_atomic_load(&ctrl[C_DONE], __ATOMIC_RELAXED,
                                 __HIP_MEMORY_SCOPE_AGENT) < GRAM_JOBS)
            __builtin_amdgcn_s_sleep(16);
    }
    __syncthreads();

    if (t < CAP) {
        u32 m = lmem[t];
        // negmin written via device-scope atomics -> read via RMW (coherence point)
        lnm[t] = (t < n) ? __uint_as_float(atomicOr(&negmin[m], 0u)) : 0.f;
        lsq[t] = (t < n) ? sq[m] : 0.f;
    }
    __syncthreads();

    // mini-gram over members; frags straight from L2-hot ebf (no LDS tile)
    u32 arowm[3];
#pragma unroll
    for (int i = 0; i < 3; ++i) arowm[i] = lmem[w * 48 + i * 16 + c16];

    float ssum = 0.f, scnt = 0.f;
    for (int cp = 0; cp < 3; ++cp) {       // col panels of 64
        if (cp * 64 >= n) break;           // block-uniform
        u32 bcolm[4];
#pragma unroll
        for (int j = 0; j < 4; ++j) bcolm[j] = lmem[cp * 64 + j * 16 + c16];

        f32x4 acc[3][4];
#pragma unroll
        for (int i = 0; i < 3; ++i)
#pragma unroll
            for (int j = 0; j < 4; ++j) acc[i][j] = (f32x4){0.f, 0.f, 0.f, 0.f};
#pragma unroll
        for (int kc = 0; kc < 4; ++kc) {
            int kch = kc * 4 + quad;
            bf16x8 a3[3], b4[4];
#pragma unroll
            for (int i = 0; i < 3; ++i) a3[i] = gA8[(size_t)arowm[i] * 16 + kch];
#pragma unroll
            for (int j = 0; j < 4; ++j) b4[j] = gA8[(size_t)bcolm[j] * 16 + kch];
#pragma unroll
            for (int i = 0; i < 3; ++i)
#pragma unroll
                for (int j = 0; j < 4; ++j)
                    acc[i][j] = __builtin_amdgcn_mfma_f32_16x16x32_bf16(a3[i], b4[j], acc[i][j], 0, 0, 0);
        }
        float lsqq[4]; u32 oq[4]; bool qv[4];
#pragma unroll
        for (int j = 0; j < 4; ++j) {
            int q = cp * 64 + j * 16 + c16;
            qv[j] = (q < n);
            lsqq[j] = qv[j] ? lsq[q] : 0.f;
            oq[j] = qv[j] ? lmem[q] : 0u;            // 0 sentinel: opp<0 never true
        }
#pragma unroll
        for (int i = 0; i < 3; ++i) {
            int pb = w * 48 + i * 16 + quad * 4;
            float rcst[4]; u32 opp[4];
#pragma unroll
            for (int rg = 0; rg < 4; ++rg) {
                int p = pb + rg;
                bool pv = (p < n);
                rcst[rg] = pv ? (lsq[p] - lnm[p] + MARGIN) : -BIGF;
                opp[rg] = pv ? lmem[p] : 0xffffffffu;   // max sentinel: opp<oq never true
            }
#pragma unroll
            for (int j = 0; j < 4; ++j)
#pragma unroll
                for (int rg = 0; rg < 4; ++rg) {
                    float val = fmaf(-2.f, acc[i][j][rg], rcst[rg] + lsqq[j]);
                    bool ok = qv[j] && (opp[rg] < oq[j]) && (val > 0.f);
                    if (ok) { ssum += val; scnt += 1.f; }
                }
        }
    }
#pragma unroll
    for (int off2 = 32; off2 > 0; off2 >>= 1) {
        ssum += __shfl_down(ssum, off2, 64);
        scnt += __shfl_down(scnt, off2, 64);
    }
    if (lane == 0) { redS[w] = ssum; redC[w] = scnt; }
    __syncthreads();
    if (t == 0) {
        atomicAdd(&totalsF[0], redS[0] + redS[1] + redS[2] + redS[3]);
        atomicAdd(&totalsF[1], redC[0] + redC[1] + redC[2] + redC[3]);
        // acq_rel ticket: orders this block's totals-adds before the count,
        // and the finalizer's reads after it — no L2-flush threadfence needed
        u32 tk = __hip_atomic_fetch_add(&ctrl[C_TK], 1u, __ATOMIC_ACQ_REL,
                                        __HIP_MEMORY_SCOPE_AGENT);
        if (tk == 63u) {
            float fs = atomicAdd(&totalsF[0], 0.f);
            float fc = atomicAdd(&totalsF[1], 0.f);
            out[0] = fs / fmaxf(fc, 1.0f);
        }
    }
}

// ---------------------------------------------------------------------------
extern "C" void kernel_launch(void* const* d_in, const int* in_sizes, int n_in,
                              void* d_out, int out_size, void* d_ws, size_t ws_size,
                              hipStream_t stream) {
    const float* emb = (const float*)d_in[0];
    const int* labels = (const int*)d_in[1];

    char* wsp = (char*)d_ws;
    u16* ebf = (u16*)wsp;
    size_t off = (size_t)N_BATCH * EMB_DIM * sizeof(u16);                // 2 MB
    float* sq = (float*)(wsp + off);       off += (size_t)N_BATCH * 4;   // 32 KB
    u32* negmin = (u32*)(wsp + off);       off += (size_t)N_BATCH * 4;   // 32 KB
    u8* labels8 = (u8*)(wsp + off);        off += N_BATCH;               // 8 KB
    u32* ctrl = (u32*)(wsp + off);         off += 512;

    k_prep<<<N_BATCH / 8, 256, 0, stream>>>(emb, labels, ebf, sq, negmin,
                                            labels8, ctrl);
    k_fused<<<GRAM_JOBS, 256, 0, stream>>>(ebf, sq, labels8, negmin, ctrl,
                                           (float*)d_out);
}

// Round 7
// 149.643 us; speedup vs baseline: 1.2615x; 1.0373x over previous
//
#include <hip/hip_runtime.h>
#include <hip/hip_bf16.h>

typedef unsigned int u32;
typedef unsigned short u16;
typedef unsigned char u8;
typedef unsigned long long u64;

#define N_BATCH 8192
#define EMB_DIM 128
#define MARGIN 1.0f
#define CAP 192          // max members/class (mean 128, sd 11.2 -> 5.7 sigma)
#define BIGF 3.3e38f
#define GRAM_JOBS 2080   // 64*65/2 triangular 128x128 tiles
#define GRID_G 1040      // 2 jobs per block

typedef __attribute__((ext_vector_type(8))) short bf16x8;   // 8 bf16 = 4 VGPRs
typedef __attribute__((ext_vector_type(4))) float f32x4;    // MFMA 16x16 acc

// async global->LDS, 16B/lane; lds dest is wave-uniform base (+lane*16 implicit)
__device__ inline void async_ld16(const void* g, void* l) {
    __builtin_amdgcn_global_load_lds(
        (const __attribute__((address_space(1))) unsigned int*)g,
        (__attribute__((address_space(3))) unsigned int*)l, 16, 0, 0);
}

// ---------------------------------------------------------------------------
// Kernel 1: bf16 cast + row sq-norms + negmin init + u8 label pack + ctrl zero.
// ---------------------------------------------------------------------------
__global__ __launch_bounds__(256) void k_prep(const float* __restrict__ emb,
                                              const int* __restrict__ labels,
                                              u16* __restrict__ ebf,
                                              float* __restrict__ sq,
                                              u32* __restrict__ negmin,
                                              u8* __restrict__ labels8,
                                              u32* __restrict__ ctrl) {
    int t = threadIdx.x;
    int gt = blockIdx.x * 256 + t;
    int r = blockIdx.x * 8 + (t >> 5);
    int l32 = t & 31;
    float4 x = ((const float4*)emb)[(size_t)r * 32 + l32];
    u32 ux = __float_as_uint(x.x), uy = __float_as_uint(x.y);
    u32 uz = __float_as_uint(x.z), uw = __float_as_uint(x.w);
    ushort4 b;
    b.x = (u16)((ux + 0x7fffu + ((ux >> 16) & 1u)) >> 16);   // RNE fp32->bf16
    b.y = (u16)((uy + 0x7fffu + ((uy >> 16) & 1u)) >> 16);
    b.z = (u16)((uz + 0x7fffu + ((uz >> 16) & 1u)) >> 16);
    b.w = (u16)((uw + 0x7fffu + ((uw >> 16) & 1u)) >> 16);
    ((ushort4*)ebf)[(size_t)r * 32 + l32] = b;

    float v = fmaf(x.x, x.x, fmaf(x.y, x.y, fmaf(x.z, x.z, x.w * x.w)));
    v += __shfl_down(v, 16, 64);   // 32-lane row reduce
    v += __shfl_down(v, 8, 64);
    v += __shfl_down(v, 4, 64);
    v += __shfl_down(v, 2, 64);
    v += __shfl_down(v, 1, 64);
    if (l32 == 0) sq[r] = v;

    if (gt < N_BATCH) {
        negmin[gt] = 0x7f7fffffu;   // FLT_MAX bits; dists clamped >=0 -> uint order == float order
        labels8[gt] = (u8)labels[gt];
    }
    if (blockIdx.x == 0 && t < 8) ctrl[t] = 0u;   // [0],[1] float totals; [2] ticket
}

// ---------------------------------------------------------------------------
// Kernel 2 (grid 1040, 2 jobs/block): triangular 128x128 Gram tile ->
// masked row/col min -> global atomicMin(negmin). minbuf is dedicated LDS
// (not B-tile reuse): 3 barriers/job, and the next job's B-DMA issues at
// loop top, overlapping the prior epilogue's in-flight global atomics.
// ---------------------------------------------------------------------------
__global__ __launch_bounds__(256, 4) void k_gram(const u16* __restrict__ ebf,
                                                 const float* __restrict__ sq,
                                                 const u8* __restrict__ labels8,
                                                 u32* __restrict__ negmin) {
    __shared__ uint4 Bs[2048];     // 32 KB B tile
    __shared__ u32 minbuf[256];    // rowmin[0..127] | colmin[128..255]

    const int t = threadIdx.x;
    const int lane = t & 63, w = t >> 6;
    const int c16 = lane & 15, quad = lane >> 4;
    const bf16x8* gA8 = (const bf16x8*)ebf;
    const uint4* gE = (const uint4*)ebf;

    int job = blockIdx.x;
    for (int jj = 0; jj < 2; ++jj, job += GRID_G) {
        // triangular decode: job -> (bx, by), by >= bx
        int idx = job;
        float ff = (129.0f - sqrtf(16641.0f - 8.0f * (float)idx)) * 0.5f;
        int bx = (int)ff;
        if (bx > 63) bx = 63;
        while (bx > 0 && idx < bx * 64 - (bx * (bx - 1)) / 2) --bx;
        while (idx >= (bx + 1) * 64 - ((bx + 1) * bx) / 2) ++bx;
        int by = bx + idx - (bx * 64 - (bx * (bx - 1)) / 2);
        const int R = bx * 128, C = by * 128;
        const bool diag = (bx == by);

        // stage B tile via DMA (prior job's B ds_reads completed before its
        // epilogue barrier; prior global atomics still in flight — fine)
#pragma unroll
        for (int it = 0; it < 8; ++it) {
            int s = w * 512 + it * 64 + lane;
            int row = s >> 4, chPos = s & 15;
            int ch = chPos ^ (row & 15);     // involutive XOR swizzle at source
            async_ld16(gE + (size_t)(C + row) * 16 + ch, Bs + (w * 512 + it * 64));
        }

        const int mb = (w & 1) * 64;
        const int nb = (w >> 1) * 64;
        bf16x8 a[4];
#pragma unroll
        for (int i = 0; i < 4; ++i)
            a[i] = gA8[(size_t)(R + mb + i * 16 + c16) * 16 + quad];

        // hoisted epilogue metadata (overlaps DMA + MFMA latency)
        float cs_[4]; int cl_[4];
#pragma unroll
        for (int j = 0; j < 4; ++j) {
            int gc = C + nb + j * 16 + c16;
            cs_[j] = sq[gc]; cl_[j] = labels8[gc];
        }
        float rs_[16]; int rl_[16];
#pragma unroll
        for (int i = 0; i < 4; ++i)
#pragma unroll
            for (int rg = 0; rg < 4; ++rg) {
                int gr = R + mb + i * 16 + quad * 4 + rg;
                rs_[i * 4 + rg] = sq[gr]; rl_[i * 4 + rg] = labels8[gr];
            }

        minbuf[t] = 0x7f7fffffu;   // each slot re-inited by the same thread that read it

        f32x4 acc[4][4];
#pragma unroll
        for (int i = 0; i < 4; ++i)
#pragma unroll
            for (int j = 0; j < 4; ++j) acc[i][j] = (f32x4){0.f, 0.f, 0.f, 0.f};

        __syncthreads();   // drains B-DMA; orders minbuf init before epilogue atomics

        const bf16x8* Bs8 = (const bf16x8*)Bs;
#pragma unroll
        for (int kc = 0; kc < 4; ++kc) {
            int kch = kc * 4 + quad;
            bf16x8 bfr[4];
#pragma unroll
            for (int j = 0; j < 4; ++j) {
                int br = nb + j * 16 + c16;
                bfr[j] = Bs8[br * 16 + (kch ^ (br & 15))];
            }
            bf16x8 an[4];
            if (kc < 3) {
                int kn = (kc + 1) * 4 + quad;
#pragma unroll
                for (int i = 0; i < 4; ++i)
                    an[i] = gA8[(size_t)(R + mb + i * 16 + c16) * 16 + kn];
            }
#pragma unroll
            for (int i = 0; i < 4; ++i)
#pragma unroll
                for (int j = 0; j < 4; ++j)
                    acc[i][j] = __builtin_amdgcn_mfma_f32_16x16x32_bf16(a[i], bfr[j], acc[i][j], 0, 0, 0);
            if (kc < 3) {
#pragma unroll
                for (int i = 0; i < 4; ++i) a[i] = an[i];
            }
        }

        // epilogue: dist, masked min, LDS atomics into dedicated minbuf
        float cm[4] = {BIGF, BIGF, BIGF, BIGF};
#pragma unroll
        for (int i = 0; i < 4; ++i) {
            const int rowbase = mb + i * 16 + quad * 4;
            float rm[4] = {BIGF, BIGF, BIGF, BIGF};
#pragma unroll
            for (int j = 0; j < 4; ++j)
#pragma unroll
                for (int rg = 0; rg < 4; ++rg) {
                    // C/D layout (m89/m91): D[row=quad*4+rg][col=lane&15]
                    float d = fmaf(-2.f, acc[i][j][rg], rs_[i * 4 + rg] + cs_[j]);
                    bool same = (rl_[i * 4 + rg] == cl_[j]);
                    float cand = same ? BIGF : fmaxf(d, 0.f);
                    rm[rg] = fminf(rm[rg], cand);
                    cm[j] = fminf(cm[j], cand);
                }
#pragma unroll
            for (int rg = 0; rg < 4; ++rg) {
                float v = rm[rg];
                v = fminf(v, __shfl_xor(v, 1, 64));
                v = fminf(v, __shfl_xor(v, 2, 64));
                v = fminf(v, __shfl_xor(v, 4, 64));
                v = fminf(v, __shfl_xor(v, 8, 64));
                if (c16 == 0) atomicMin(&minbuf[rowbase + rg], __float_as_uint(v));
            }
        }
        if (!diag) {
#pragma unroll
            for (int j = 0; j < 4; ++j) {
                float v = cm[j];
                v = fminf(v, __shfl_xor(v, 16, 64));
                v = fminf(v, __shfl_xor(v, 32, 64));
                if (quad == 0) atomicMin(&minbuf[128 + nb + j * 16 + c16], __float_as_uint(v));
            }
        }
        __syncthreads();   // minbuf complete; also: all B ds_reads done (K-loop) before next DMA

        if (t < 128) atomicMin(&negmin[R + t], minbuf[t]);
        else if (!diag) atomicMin(&negmin[C + t - 128], minbuf[t]);
        // global atomics are fire-and-forget; next job's DMA issues immediately
    }
}

// ---------------------------------------------------------------------------
// Kernel 3 (64 blocks): per-class pair losses. Ballot-scan labels8 -> member
// list; stage member rows into LDS (coalesced 256B row gathers); mini-MFMA
// Gram from LDS; val = d - negmin[anchor] + m; ticket-last block finalizes.
// ---------------------------------------------------------------------------
__global__ __launch_bounds__(256) void k_class(const u16* __restrict__ ebf,
                                               const float* __restrict__ sq,
                                               const u8* __restrict__ labels8,
                                               const u32* __restrict__ negmin,
                                               u32* __restrict__ ctrl,
                                               float* __restrict__ out) {
    const int c = blockIdx.x;
    __shared__ uint4 Es[3072];      // 48 KB: 192 member rows, XOR-swizzled
    __shared__ u32 lmem[CAP];
    __shared__ float lnm[CAP], lsq[CAP];
    __shared__ float redS[4], redC[4];
    __shared__ u32 sN;

    const int t = threadIdx.x;
    const int lane = t & 63, w = t >> 6;
    const int c16 = lane & 15, quad = lane >> 4;
    float* totalsF = (float*)ctrl;

    if (t == 0) sN = 0u;
    __syncthreads();
    for (int ch = 0; ch < 32; ++ch) {   // ballot member scan over 8KB labels8
        int row = ch * 256 + t;
        bool m = (labels8[row] == (u8)c);
        u64 mask = __ballot(m);
        u32 base = 0;
        if (lane == 0 && mask) base = atomicAdd(&sN, (u32)__popcll(mask));
        base = __shfl(base, 0, 64);
        if (m) {
            u32 p = base + (u32)__popcll(mask & ((1ull << lane) - 1ull));
            if (p < CAP) lmem[p] = (u32)row;
        }
    }
    __syncthreads();
    int n = (int)sN; if (n > CAP) n = CAP;
    if (t < CAP && t >= n) lmem[t] = 0u;   // pad -> row 0 (masked below)
    __syncthreads();

    if (t < CAP) {
        u32 m = lmem[t];
        // cross-kernel boundary: k_gram's atomic results visible to plain loads
        lnm[t] = (t < n) ? __uint_as_float(negmin[m]) : 0.f;
        lsq[t] = (t < n) ? sq[m] : 0.f;
    }
    const uint4* gE = (const uint4*)ebf;
#pragma unroll
    for (int it = 0; it < 12; ++it) {      // gather 192 rows (256B coalesced each)
        int s = t + it * 256;
        int row = s >> 4, ch = s & 15;
        u32 m = lmem[row];
        Es[row * 16 + (ch ^ (row & 15))] = gE[(size_t)m * 16 + ch];
    }
    __syncthreads();

    const bf16x8* Es8 = (const bf16x8*)Es;
    float ssum = 0.f, scnt = 0.f;
    for (int cp = 0; cp < 3; ++cp) {       // col panels of 64; wave w owns rows w*48..+47
        if (cp * 64 >= n) break;           // block-uniform
        f32x4 acc[3][4];
#pragma unroll
        for (int i = 0; i < 3; ++i)
#pragma unroll
            for (int j = 0; j < 4; ++j) acc[i][j] = (f32x4){0.f, 0.f, 0.f, 0.f};
#pragma unroll
        for (int kc = 0; kc < 4; ++kc) {
            int kch = kc * 4 + quad;
            bf16x8 a3[3], b4[4];
#pragma unroll
            for (int i = 0; i < 3; ++i) {
                int ar = w * 48 + i * 16 + c16;
                a3[i] = Es8[ar * 16 + (kch ^ (ar & 15))];
            }
#pragma unroll
            for (int j = 0; j < 4; ++j) {
                int br = cp * 64 + j * 16 + c16;
                b4[j] = Es8[br * 16 + (kch ^ (br & 15))];
            }
#pragma unroll
            for (int i = 0; i < 3; ++i)
#pragma unroll
                for (int j = 0; j < 4; ++j)
                    acc[i][j] = __builtin_amdgcn_mfma_f32_16x16x32_bf16(a3[i], b4[j], acc[i][j], 0, 0, 0);
        }
        float lsqq[4]; u32 oq[4]; bool qv[4];
#pragma unroll
        for (int j = 0; j < 4; ++j) {
            int q = cp * 64 + j * 16 + c16;
            qv[j] = (q < n);
            lsqq[j] = qv[j] ? lsq[q] : 0.f;
            oq[j] = qv[j] ? lmem[q] : 0u;            // 0 sentinel: opp<0 never true
        }
#pragma unroll
        for (int i = 0; i < 3; ++i) {
            int pb = w * 48 + i * 16 + quad * 4;
            float rcst[4]; u32 opp[4];
#pragma unroll
            for (int rg = 0; rg < 4; ++rg) {
                int p = pb + rg;
                bool pv = (p < n);
                rcst[rg] = pv ? (lsq[p] - lnm[p] + MARGIN) : -BIGF;
                opp[rg] = pv ? lmem[p] : 0xffffffffu;   // max sentinel: opp<oq never true
            }
#pragma unroll
            for (int j = 0; j < 4; ++j)
#pragma unroll
                for (int rg = 0; rg < 4; ++rg) {
                    float val = fmaf(-2.f, acc[i][j][rg], rcst[rg] + lsqq[j]);
                    bool ok = qv[j] && (opp[rg] < oq[j]) && (val > 0.f);
                    if (ok) { ssum += val; scnt += 1.f; }
                }
        }
    }
#pragma unroll
    for (int off2 = 32; off2 > 0; off2 >>= 1) {
        ssum += __shfl_down(ssum, off2, 64);
        scnt += __shfl_down(scnt, off2, 64);
    }
    if (lane == 0) { redS[w] = ssum; redC[w] = scnt; }
    __syncthreads();
    if (t == 0) {
        atomicAdd(&totalsF[0], redS[0] + redS[1] + redS[2] + redS[3]);
        atomicAdd(&totalsF[1], redC[0] + redC[1] + redC[2] + redC[3]);
        u32 tk = __hip_atomic_fetch_add(&ctrl[2], 1u, __ATOMIC_ACQ_REL,
                                        __HIP_MEMORY_SCOPE_AGENT);
        if (tk == 63u) {                    // last class block finalizes
            float fs = atomicAdd(&totalsF[0], 0.f);
            float fc = atomicAdd(&totalsF[1], 0.f);
            out[0] = fs / fmaxf(fc, 1.0f);
        }
    }
}

// ---------------------------------------------------------------------------
extern "C" void kernel_launch(void* const* d_in, const int* in_sizes, int n_in,
                              void* d_out, int out_size, void* d_ws, size_t ws_size,
                              hipStream_t stream) {
    const float* emb = (const float*)d_in[0];
    const int* labels = (const int*)d_in[1];

    char* wsp = (char*)d_ws;
    u16* ebf = (u16*)wsp;
    size_t off = (size_t)N_BATCH * EMB_DIM * sizeof(u16);                // 2 MB
    float* sq = (float*)(wsp + off);       off += (size_t)N_BATCH * 4;   // 32 KB
    u32* negmin = (u32*)(wsp + off);       off += (size_t)N_BATCH * 4;   // 32 KB
    u8* labels8 = (u8*)(wsp + off);        off += N_BATCH;               // 8 KB
    u32* ctrl = (u32*)(wsp + off);         off += 512;

    k_prep<<<N_BATCH / 8, 256, 0, stream>>>(emb, labels, ebf, sq, negmin,
                                            labels8, ctrl);
    k_gram<<<GRID_G, 256, 0, stream>>>(ebf, sq, labels8, negmin);
    k_class<<<64, 256, 0, stream>>>(ebf, sq, labels8, negmin, ctrl, (float*)d_out);
}

// Round 8
// 120.205 us; speedup vs baseline: 1.5704x; 1.2449x over previous
//
#include <hip/hip_runtime.h>
#include <hip/hip_bf16.h>

typedef unsigned int u32;
typedef unsigned short u16;
typedef unsigned char u8;
typedef unsigned long long u64;

#define N_BATCH 8192
#define EMB_DIM 128
#define MARGIN 1.0f
#define CAP 192          // max members/class (mean 128, sd 11.2 -> 5.7 sigma)
#define BIGF 3.3e38f
#define GRAM_JOBS 2080   // 64*65/2 triangular 128x128 tiles

typedef __attribute__((ext_vector_type(8))) short bf16x8;   // 8 bf16 = 4 VGPRs
typedef __attribute__((ext_vector_type(4))) float f32x4;    // MFMA 16x16 acc

// async global->LDS, 16B/lane; lds dest is wave-uniform base (+lane*16 implicit)
__device__ inline void async_ld16(const void* g, void* l) {
    __builtin_amdgcn_global_load_lds(
        (const __attribute__((address_space(1))) unsigned int*)g,
        (__attribute__((address_space(3))) unsigned int*)l, 16, 0, 0);
}

// ---------------------------------------------------------------------------
// Kernel 1: bf16 cast + row sq-norms + u8 label pack + ctrl zero.
// ---------------------------------------------------------------------------
__global__ __launch_bounds__(256) void k_prep(const float* __restrict__ emb,
                                              const int* __restrict__ labels,
                                              u16* __restrict__ ebf,
                                              float* __restrict__ sq,
                                              u8* __restrict__ labels8,
                                              u32* __restrict__ ctrl) {
    int t = threadIdx.x;
    int gt = blockIdx.x * 256 + t;
    int r = blockIdx.x * 8 + (t >> 5);
    int l32 = t & 31;
    float4 x = ((const float4*)emb)[(size_t)r * 32 + l32];
    u32 ux = __float_as_uint(x.x), uy = __float_as_uint(x.y);
    u32 uz = __float_as_uint(x.z), uw = __float_as_uint(x.w);
    ushort4 b;
    b.x = (u16)((ux + 0x7fffu + ((ux >> 16) & 1u)) >> 16);   // RNE fp32->bf16
    b.y = (u16)((uy + 0x7fffu + ((uy >> 16) & 1u)) >> 16);
    b.z = (u16)((uz + 0x7fffu + ((uz >> 16) & 1u)) >> 16);
    b.w = (u16)((uw + 0x7fffu + ((uw >> 16) & 1u)) >> 16);
    ((ushort4*)ebf)[(size_t)r * 32 + l32] = b;

    float v = fmaf(x.x, x.x, fmaf(x.y, x.y, fmaf(x.z, x.z, x.w * x.w)));
    v += __shfl_down(v, 16, 64);   // 32-lane row reduce
    v += __shfl_down(v, 8, 64);
    v += __shfl_down(v, 4, 64);
    v += __shfl_down(v, 2, 64);
    v += __shfl_down(v, 1, 64);
    if (l32 == 0) sq[r] = v;

    if (gt < N_BATCH) labels8[gt] = (u8)labels[gt];
    if (blockIdx.x == 0 && t < 8) ctrl[t] = 0u;   // [0],[1] float totals; [2] ticket
}

// ---------------------------------------------------------------------------
// Kernel 2 (grid 2080, 1 job/block): triangular 128x128 Gram tile ->
// masked row/col min -> PLAIN coalesced stores into partial[64][8192].
// Slot coverage for row r in block-row bx: o<bx from col-side of tile (o,bx),
// o==bx from diag row-side, o>bx from row-side of (bx,o) — each slot written
// exactly once, zero global atomics.
// ---------------------------------------------------------------------------
__global__ __launch_bounds__(256, 4) void k_gram(const u16* __restrict__ ebf,
                                                 const float* __restrict__ sq,
                                                 const u8* __restrict__ labels8,
                                                 u32* __restrict__ partial) {
    __shared__ uint4 Bs[2048];     // 32 KB B tile
    __shared__ u32 minbuf[256];    // rowmin[0..127] | colmin[128..255]

    const int t = threadIdx.x;
    const int lane = t & 63, w = t >> 6;
    const int c16 = lane & 15, quad = lane >> 4;
    const bf16x8* gA8 = (const bf16x8*)ebf;
    const uint4* gE = (const uint4*)ebf;

    // triangular decode: blockIdx.x -> (bx, by), by >= bx
    int idx = blockIdx.x;
    float ff = (129.0f - sqrtf(16641.0f - 8.0f * (float)idx)) * 0.5f;
    int bx = (int)ff;
    if (bx > 63) bx = 63;
    while (bx > 0 && idx < bx * 64 - (bx * (bx - 1)) / 2) --bx;
    while (idx >= (bx + 1) * 64 - ((bx + 1) * bx) / 2) ++bx;
    int by = bx + idx - (bx * 64 - (bx * (bx - 1)) / 2);
    const int R = bx * 128, C = by * 128;
    const bool diag = (bx == by);

    // stage B tile via DMA, XOR swizzle folded into source address
#pragma unroll
    for (int it = 0; it < 8; ++it) {
        int s = w * 512 + it * 64 + lane;
        int row = s >> 4, chPos = s & 15;
        int ch = chPos ^ (row & 15);
        async_ld16(gE + (size_t)(C + row) * 16 + ch, Bs + (w * 512 + it * 64));
    }

    const int mb = (w & 1) * 64;
    const int nb = (w >> 1) * 64;
    bf16x8 a[4];
#pragma unroll
    for (int i = 0; i < 4; ++i)
        a[i] = gA8[(size_t)(R + mb + i * 16 + c16) * 16 + quad];

    // hoisted epilogue metadata (overlaps DMA + MFMA latency)
    float cs_[4]; int cl_[4];
#pragma unroll
    for (int j = 0; j < 4; ++j) {
        int gc = C + nb + j * 16 + c16;
        cs_[j] = sq[gc]; cl_[j] = labels8[gc];
    }
    float rs_[16]; int rl_[16];
#pragma unroll
    for (int i = 0; i < 4; ++i)
#pragma unroll
        for (int rg = 0; rg < 4; ++rg) {
            int gr = R + mb + i * 16 + quad * 4 + rg;
            rs_[i * 4 + rg] = sq[gr]; rl_[i * 4 + rg] = labels8[gr];
        }

    minbuf[t] = 0x7f7fffffu;

    f32x4 acc[4][4];
#pragma unroll
    for (int i = 0; i < 4; ++i)
#pragma unroll
        for (int j = 0; j < 4; ++j) acc[i][j] = (f32x4){0.f, 0.f, 0.f, 0.f};

    __syncthreads();   // drains B-DMA; orders minbuf init

    const bf16x8* Bs8 = (const bf16x8*)Bs;
#pragma unroll
    for (int kc = 0; kc < 4; ++kc) {
        int kch = kc * 4 + quad;
        bf16x8 bfr[4];
#pragma unroll
        for (int j = 0; j < 4; ++j) {
            int br = nb + j * 16 + c16;
            bfr[j] = Bs8[br * 16 + (kch ^ (br & 15))];
        }
        bf16x8 an[4];
        if (kc < 3) {
            int kn = (kc + 1) * 4 + quad;
#pragma unroll
            for (int i = 0; i < 4; ++i)
                an[i] = gA8[(size_t)(R + mb + i * 16 + c16) * 16 + kn];
        }
#pragma unroll
        for (int i = 0; i < 4; ++i)
#pragma unroll
            for (int j = 0; j < 4; ++j)
                acc[i][j] = __builtin_amdgcn_mfma_f32_16x16x32_bf16(a[i], bfr[j], acc[i][j], 0, 0, 0);
        if (kc < 3) {
#pragma unroll
            for (int i = 0; i < 4; ++i) a[i] = an[i];
        }
    }

    // epilogue: dist, masked min, LDS atomics into minbuf
    float cm[4] = {BIGF, BIGF, BIGF, BIGF};
#pragma unroll
    for (int i = 0; i < 4; ++i) {
        const int rowbase = mb + i * 16 + quad * 4;
        float rm[4] = {BIGF, BIGF, BIGF, BIGF};
#pragma unroll
        for (int j = 0; j < 4; ++j)
#pragma unroll
            for (int rg = 0; rg < 4; ++rg) {
                // C/D layout (m89/m91): D[row=quad*4+rg][col=lane&15]
                float d = fmaf(-2.f, acc[i][j][rg], rs_[i * 4 + rg] + cs_[j]);
                bool same = (rl_[i * 4 + rg] == cl_[j]);
                float cand = same ? BIGF : fmaxf(d, 0.f);
                rm[rg] = fminf(rm[rg], cand);
                cm[j] = fminf(cm[j], cand);
            }
#pragma unroll
        for (int rg = 0; rg < 4; ++rg) {
            float v = rm[rg];
            v = fminf(v, __shfl_xor(v, 1, 64));
            v = fminf(v, __shfl_xor(v, 2, 64));
            v = fminf(v, __shfl_xor(v, 4, 64));
            v = fminf(v, __shfl_xor(v, 8, 64));
            if (c16 == 0) atomicMin(&minbuf[rowbase + rg], __float_as_uint(v));
        }
    }
    if (!diag) {
#pragma unroll
        for (int j = 0; j < 4; ++j) {
            float v = cm[j];
            v = fminf(v, __shfl_xor(v, 16, 64));
            v = fminf(v, __shfl_xor(v, 32, 64));
            if (quad == 0) atomicMin(&minbuf[128 + nb + j * 16 + c16], __float_as_uint(v));
        }
    }
    __syncthreads();

    // plain coalesced stores — each slot has exactly one writer
    if (t < 128) partial[(size_t)by * N_BATCH + R + t] = minbuf[t];
    else if (!diag) partial[(size_t)bx * N_BATCH + C + (t - 128)] = minbuf[t];
}

// ---------------------------------------------------------------------------
// Kernel 3 (64 blocks): per-class pair losses. Ballot-scan labels8 -> member
// list; reduce members' negmin from partial[64][8192]; stage member rows into
// LDS; mini-MFMA Gram; val = d - negmin[anchor] + m; ticket-last finalizes.
// ---------------------------------------------------------------------------
__global__ __launch_bounds__(256) void k_class(const u16* __restrict__ ebf,
                                               const float* __restrict__ sq,
                                               const u8* __restrict__ labels8,
                                               const u32* __restrict__ partial,
                                               u32* __restrict__ ctrl,
                                               float* __restrict__ out) {
    const int c = blockIdx.x;
    __shared__ uint4 Es[3072];      // 48 KB: 192 member rows, XOR-swizzled
    __shared__ u32 lmem[CAP];
    __shared__ float lnm[CAP], lsq[CAP];
    __shared__ float redS[4], redC[4];
    __shared__ u32 sN;

    const int t = threadIdx.x;
    const int lane = t & 63, w = t >> 6;
    const int c16 = lane & 15, quad = lane >> 4;
    float* totalsF = (float*)ctrl;

    if (t == 0) sN = 0u;
    __syncthreads();
    for (int ch = 0; ch < 32; ++ch) {   // ballot member scan over 8KB labels8
        int row = ch * 256 + t;
        bool m = (labels8[row] == (u8)c);
        u64 mask = __ballot(m);
        u32 base = 0;
        if (lane == 0 && mask) base = atomicAdd(&sN, (u32)__popcll(mask));
        base = __shfl(base, 0, 64);
        if (m) {
            u32 p = base + (u32)__popcll(mask & ((1ull << lane) - 1ull));
            if (p < CAP) lmem[p] = (u32)row;
        }
    }
    __syncthreads();
    int n = (int)sN; if (n > CAP) n = CAP;
    if (t < CAP && t >= n) lmem[t] = 0u;   // pad -> row 0 (masked below)
    __syncthreads();

    if (t < CAP) {
        u32 m = lmem[t];
        u32 mn = 0x7f7fffffu;              // reduce 64 partials for this member
#pragma unroll
        for (int o = 0; o < 64; ++o) mn = min(mn, partial[(size_t)o * N_BATCH + m]);
        lnm[t] = __uint_as_float(mn);
        lsq[t] = (t < n) ? sq[m] : 0.f;
    }
    const uint4* gE = (const uint4*)ebf;
#pragma unroll
    for (int it = 0; it < 12; ++it) {      // gather 192 rows (256B coalesced each)
        int s = t + it * 256;
        int row = s >> 4, ch = s & 15;
        u32 m = lmem[row];
        Es[row * 16 + (ch ^ (row & 15))] = gE[(size_t)m * 16 + ch];
    }
    __syncthreads();

    const bf16x8* Es8 = (const bf16x8*)Es;
    float ssum = 0.f, scnt = 0.f;
    for (int cp = 0; cp < 3; ++cp) {       // col panels of 64; wave w owns rows w*48..+47
        if (cp * 64 >= n) break;           // block-uniform
        f32x4 acc[3][4];
#pragma unroll
        for (int i = 0; i < 3; ++i)
#pragma unroll
            for (int j = 0; j < 4; ++j) acc[i][j] = (f32x4){0.f, 0.f, 0.f, 0.f};
#pragma unroll
        for (int kc = 0; kc < 4; ++kc) {
            int kch = kc * 4 + quad;
            bf16x8 a3[3], b4[4];
#pragma unroll
            for (int i = 0; i < 3; ++i) {
                int ar = w * 48 + i * 16 + c16;
                a3[i] = Es8[ar * 16 + (kch ^ (ar & 15))];
            }
#pragma unroll
            for (int j = 0; j < 4; ++j) {
                int br = cp * 64 + j * 16 + c16;
                b4[j] = Es8[br * 16 + (kch ^ (br & 15))];
            }
#pragma unroll
            for (int i = 0; i < 3; ++i)
#pragma unroll
                for (int j = 0; j < 4; ++j)
                    acc[i][j] = __builtin_amdgcn_mfma_f32_16x16x32_bf16(a3[i], b4[j], acc[i][j], 0, 0, 0);
        }
        float lsqq[4]; u32 oq[4]; bool qv[4];
#pragma unroll
        for (int j = 0; j < 4; ++j) {
            int q = cp * 64 + j * 16 + c16;
            qv[j] = (q < n);
            lsqq[j] = qv[j] ? lsq[q] : 0.f;
            oq[j] = qv[j] ? lmem[q] : 0u;            // 0 sentinel: opp<0 never true
        }
#pragma unroll
        for (int i = 0; i < 3; ++i) {
            int pb = w * 48 + i * 16 + quad * 4;
            float rcst[4]; u32 opp[4];
#pragma unroll
            for (int rg = 0; rg < 4; ++rg) {
                int p = pb + rg;
                bool pv = (p < n);
                rcst[rg] = pv ? (lsq[p] - lnm[p] + MARGIN) : -BIGF;
                opp[rg] = pv ? lmem[p] : 0xffffffffu;   // max sentinel: opp<oq never true
            }
#pragma unroll
            for (int j = 0; j < 4; ++j)
#pragma unroll
                for (int rg = 0; rg < 4; ++rg) {
                    float val = fmaf(-2.f, acc[i][j][rg], rcst[rg] + lsqq[j]);
                    bool ok = qv[j] && (opp[rg] < oq[j]) && (val > 0.f);
                    if (ok) { ssum += val; scnt += 1.f; }
                }
        }
    }
#pragma unroll
    for (int off2 = 32; off2 > 0; off2 >>= 1) {
        ssum += __shfl_down(ssum, off2, 64);
        scnt += __shfl_down(scnt, off2, 64);
    }
    if (lane == 0) { redS[w] = ssum; redC[w] = scnt; }
    __syncthreads();
    if (t == 0) {
        atomicAdd(&totalsF[0], redS[0] + redS[1] + redS[2] + redS[3]);
        atomicAdd(&totalsF[1], redC[0] + redC[1] + redC[2] + redC[3]);
        u32 tk = __hip_atomic_fetch_add(&ctrl[2], 1u, __ATOMIC_ACQ_REL,
                                        __HIP_MEMORY_SCOPE_AGENT);
        if (tk == 63u) {                    // last class block finalizes
            float fs = atomicAdd(&totalsF[0], 0.f);
            float fc = atomicAdd(&totalsF[1], 0.f);
            out[0] = fs / fmaxf(fc, 1.0f);
        }
    }
}

// ---------------------------------------------------------------------------
extern "C" void kernel_launch(void* const* d_in, const int* in_sizes, int n_in,
                              void* d_out, int out_size, void* d_ws, size_t ws_size,
                              hipStream_t stream) {
    const float* emb = (const float*)d_in[0];
    const int* labels = (const int*)d_in[1];

    char* wsp = (char*)d_ws;
    u16* ebf = (u16*)wsp;
    size_t off = (size_t)N_BATCH * EMB_DIM * sizeof(u16);                  // 2 MB
    float* sq = (float*)(wsp + off);     off += (size_t)N_BATCH * 4;       // 32 KB
    u8* labels8 = (u8*)(wsp + off);      off += N_BATCH;                   // 8 KB
    u32* ctrl = (u32*)(wsp + off);       off += 512;
    u32* partial = (u32*)(wsp + off);    off += (size_t)64 * N_BATCH * 4;  // 2 MB

    k_prep<<<N_BATCH / 8, 256, 0, stream>>>(emb, labels, ebf, sq, labels8, ctrl);
    k_gram<<<GRAM_JOBS, 256, 0, stream>>>(ebf, sq, labels8, partial);
    k_class<<<64, 256, 0, stream>>>(ebf, sq, labels8, partial, ctrl, (float*)d_out);
}